// Round 21
// baseline (685.458 us; speedup 1.0000x reference)
//
#include <hip/hip_runtime.h>

// ---------------- CSR build ----------------

__global__ void degree_kernel(const int* __restrict__ ei, int* __restrict__ deg, int E) {
    int e = blockIdx.x * blockDim.x + threadIdx.x;
    if (e < E) {
        int dst = ei[E + e];
        atomicAdd(&deg[dst], 1);
    }
}

__global__ __launch_bounds__(512) void block_sum_kernel(
    const int* __restrict__ deg, int* __restrict__ bsum, int n)
{
    __shared__ int s[512];
    int i = blockIdx.x * 512 + threadIdx.x;
    s[threadIdx.x] = (i < n) ? deg[i] : 0;
    __syncthreads();
#pragma unroll
    for (int off = 256; off > 0; off >>= 1) {
        if (threadIdx.x < off) s[threadIdx.x] += s[threadIdx.x + off];
        __syncthreads();
    }
    if (threadIdx.x == 0) bsum[blockIdx.x] = s[0];
}

__global__ __launch_bounds__(1024) void bsum_scan_kernel(int* __restrict__ bsum, int nb) {
    __shared__ int s[1024];
    int t = threadIdx.x;
    s[t] = (t < nb) ? bsum[t] : 0;
    __syncthreads();
    for (int off = 1; off < 1024; off <<= 1) {
        int v = 0;
        if (t >= off) v = s[t - off];
        __syncthreads();
        if (t >= off) s[t] += v;
        __syncthreads();
    }
    if (t < nb) bsum[t] = (t == 0) ? 0 : s[t - 1];
}

__global__ __launch_bounds__(512) void scan_write_kernel(
    const int* __restrict__ deg, const int* __restrict__ bsum,
    int* __restrict__ offs, float* __restrict__ invd, int n, int E)
{
    __shared__ int s[512];
    int t = threadIdx.x;
    int i = blockIdx.x * 512 + t;
    int d = (i < n) ? deg[i] : 0;
    s[t] = d;
    __syncthreads();
    for (int off = 1; off < 512; off <<= 1) {
        int v = 0;
        if (t >= off) v = s[t - off];
        __syncthreads();
        if (t >= off) s[t] += v;
        __syncthreads();
    }
    if (i < n) {
        offs[i] = bsum[blockIdx.x] + s[t] - d;   // exclusive prefix
        invd[i] = 1.0f / (float)(d > 0 ? d : 1);
    }
    if (blockIdx.x == 0 && t == 0) offs[n] = E;
}

__global__ void fill_kernel(const int* __restrict__ ei, const int* __restrict__ offs,
                            int* __restrict__ cursor, int* __restrict__ csr, int E) {
    int e = blockIdx.x * blockDim.x + threadIdx.x;
    if (e < E) {
        int src = ei[e];
        int dst = ei[E + e];
        int pos = atomicAdd(&cursor[dst], 1);
        csr[offs[dst] + pos] = src;
    }
}

// ---------------- fp32 -> bf16 conversion (RNE) ----------------

__device__ inline unsigned short f2bf(float f) {
    unsigned int u = __float_as_uint(f);
    return (unsigned short)((u + 0x7fffu + ((u >> 16) & 1u)) >> 16);
}

__device__ inline float bflo(unsigned int u) { return __uint_as_float(u << 16); }
__device__ inline float bfhi(unsigned int u) { return __uint_as_float(u & 0xffff0000u); }

__global__ void f32_to_bf16_kernel(const float* __restrict__ in,
                                   unsigned short* __restrict__ out, int n4) {
    int i = blockIdx.x * blockDim.x + threadIdx.x;
    if (i < n4) {
        float4 v = *(const float4*)(in + (size_t)i * 4);
        ushort4 o;
        o.x = f2bf(v.x); o.y = f2bf(v.y); o.z = f2bf(v.z); o.w = f2bf(v.w);
        *(ushort4*)(out + (size_t)i * 4) = o;
    }
}

// ---------------- mean aggregation over bf16 rows (fp32 accumulate) ----------

__device__ inline void addbf8(float* a, uint4 v) {
    a[0] += bflo(v.x); a[1] += bfhi(v.x);
    a[2] += bflo(v.y); a[3] += bfhi(v.y);
    a[4] += bflo(v.z); a[5] += bfhi(v.z);
    a[6] += bflo(v.w); a[7] += bfhi(v.w);
}

template <int D>
__global__ __launch_bounds__(256) void aggregate_bf16_kernel(
    const unsigned short* __restrict__ hb, const int* __restrict__ offs,
    const int* __restrict__ csr, const float* __restrict__ invd,
    unsigned short* __restrict__ meanb, int nN)
{
    constexpr int LPR = D / 8;      // lanes per row (16 for D=128, 8 for D=64)
    constexpr int G = 64 / LPR;     // neighbor groups per wave (4 or 8)
    int wid = blockIdx.x * 4 + (threadIdx.x >> 6);
    int lane = threadIdx.x & 63;
    if (wid >= nN) return;
    int o0 = offs[wid], o1 = offs[wid + 1];
    const int p = lane / LPR;
    const int col = (lane % LPR) * 8;

    float a0[8] = {0.f, 0.f, 0.f, 0.f, 0.f, 0.f, 0.f, 0.f};
    float a1[8] = {0.f, 0.f, 0.f, 0.f, 0.f, 0.f, 0.f, 0.f};
    int j = o0;
    for (; j + 2 * G <= o1; j += 2 * G) {
        int s0 = csr[j + p];
        int s1 = csr[j + G + p];
        uint4 v0 = *(const uint4*)(hb + (size_t)s0 * D + col);
        uint4 v1 = *(const uint4*)(hb + (size_t)s1 * D + col);
        addbf8(a0, v0);
        addbf8(a1, v1);
    }
    if (j + G <= o1) {
        int s0 = csr[j + p];
        uint4 v0 = *(const uint4*)(hb + (size_t)s0 * D + col);
        addbf8(a0, v0);
        j += G;
    }
    if (j < o1 && p < o1 - j) {      // partial group
        int s1 = csr[j + p];
        uint4 v1 = *(const uint4*)(hb + (size_t)s1 * D + col);
        addbf8(a1, v1);
    }
#pragma unroll
    for (int q = 0; q < 8; q++) a0[q] += a1[q];

#pragma unroll
    for (int m = LPR; m < 64; m <<= 1) {
#pragma unroll
        for (int q = 0; q < 8; q++) a0[q] += __shfl_xor(a0[q], m);
    }

    if (lane < LPR) {
        float iv = invd[wid];
        uint4 o;
        o.x = (unsigned)f2bf(a0[0] * iv) | ((unsigned)f2bf(a0[1] * iv) << 16);
        o.y = (unsigned)f2bf(a0[2] * iv) | ((unsigned)f2bf(a0[3] * iv) << 16);
        o.z = (unsigned)f2bf(a0[4] * iv) | ((unsigned)f2bf(a0[5] * iv) << 16);
        o.w = (unsigned)f2bf(a0[6] * iv) | ((unsigned)f2bf(a0[7] * iv) << 16);
        *(uint4*)(meanb + (size_t)wid * D + col) = o;
    }
}

// ---------------- fused dual GEMM + bias + ReLU, W in LDS, bf16 A (uint2) -----
// ROUND-14 STRUCTURE (full/partial branch OUTSIDE k-loop; single-chunk A loads
// only — multi-chunk A buffering spilled in r11/r13/r15/r19). Round-21: R=8
// for layers 1-2 — halves chunk count, halves per-chunk-stall total; VGPR ~90.

__device__ inline void fma4(float4& a, float s, const float4& w) {
    a.x = fmaf(s, w.x, a.x);
    a.y = fmaf(s, w.y, a.y);
    a.z = fmaf(s, w.z, a.z);
    a.w = fmaf(s, w.w, a.w);
}

template <int K, int M, int R, int NS>
__global__ __launch_bounds__(512, 4) void gemm_relu_ldsw(
    const unsigned short* __restrict__ A1, const unsigned short* __restrict__ A2,
    const float* __restrict__ wl, const float* __restrict__ wr,
    const float* __restrict__ bias, float* __restrict__ out,
    unsigned short* __restrict__ outb, int nN)
{
    constexpr int KQ = K / NS;            // k-slice staged at a time (mult of 4)
    constexpr int TXc = M / 4;            // threads per row-group
    constexpr int GROUPS = 512 / TXc;
    constexpr int ROWS = GROUPS * R;      // rows per block
    constexpr int F4 = KQ * M / 4;        // float4s per matrix slice

    __shared__ float ws[2 * KQ * M];      // [0..) = wl slice, [KQ*M..) = wr slice

    const int tid = threadIdx.x;
    const int cq = (tid % TXc) * 4;
    const int g = tid / TXc;
    const int nbase = blockIdx.x * ROWS;
    const int n0 = nbase + g * R;
    const bool full = (nbase + ROWS <= nN);

    const float4 bv = *(const float4*)(bias + cq);
    float4 acc[R];
#pragma unroll
    for (int rr = 0; rr < R; rr++) acc[rr] = bv;

#pragma unroll
    for (int s = 0; s < NS; s++) {
        __syncthreads();                   // previous slice's compute done
        const float4* wlg = (const float4*)(wl + (size_t)s * KQ * M);
        const float4* wrg = (const float4*)(wr + (size_t)s * KQ * M);
        float4* s0 = (float4*)ws;
        float4* s1 = (float4*)(ws + KQ * M);
        for (int i = tid; i < F4; i += 512) {
            s0[i] = wlg[i];
            s1[i] = wrg[i];
        }
        __syncthreads();

        const int kbase = s * KQ;
        if (full) {
            const unsigned short* __restrict__ a1p = A1 + (size_t)n0 * K + kbase;
            const unsigned short* __restrict__ a2p = A2 + (size_t)n0 * K + kbase;
            for (int kk0 = 0; kk0 < KQ; kk0 += 4) {
                uint2 a1v[R], a2v[R];
#pragma unroll
                for (int rr = 0; rr < R; rr++) {
                    a1v[rr] = *(const uint2*)(a1p + (size_t)rr * K + kk0);
                    a2v[rr] = *(const uint2*)(a2p + (size_t)rr * K + kk0);
                }
                float4 wlv[4], wrv[4];
#pragma unroll
                for (int j = 0; j < 4; j++) {
                    wlv[j] = *(const float4*)(&ws[(kk0 + j) * M + cq]);
                    wrv[j] = *(const float4*)(&ws[KQ * M + (kk0 + j) * M + cq]);
                }
#pragma unroll
                for (int rr = 0; rr < R; rr++) {
                    fma4(acc[rr], bflo(a1v[rr].x), wlv[0]);
                    fma4(acc[rr], bfhi(a1v[rr].x), wlv[1]);
                    fma4(acc[rr], bflo(a1v[rr].y), wlv[2]);
                    fma4(acc[rr], bfhi(a1v[rr].y), wlv[3]);
                    fma4(acc[rr], bflo(a2v[rr].x), wrv[0]);
                    fma4(acc[rr], bfhi(a2v[rr].x), wrv[1]);
                    fma4(acc[rr], bflo(a2v[rr].y), wrv[2]);
                    fma4(acc[rr], bfhi(a2v[rr].y), wrv[3]);
                }
            }
        } else {
            for (int kk0 = 0; kk0 < KQ; kk0 += 4) {
                float4 wlv[4], wrv[4];
#pragma unroll
                for (int j = 0; j < 4; j++) {
                    wlv[j] = *(const float4*)(&ws[(kk0 + j) * M + cq]);
                    wrv[j] = *(const float4*)(&ws[KQ * M + (kk0 + j) * M + cq]);
                }
#pragma unroll
                for (int rr = 0; rr < R; rr++) {
                    int n = n0 + rr;
                    if (n < nN) {
                        uint2 a1 = *(const uint2*)(A1 + (size_t)n * K + kbase + kk0);
                        uint2 a2 = *(const uint2*)(A2 + (size_t)n * K + kbase + kk0);
                        fma4(acc[rr], bflo(a1.x), wlv[0]);
                        fma4(acc[rr], bfhi(a1.x), wlv[1]);
                        fma4(acc[rr], bflo(a1.y), wlv[2]);
                        fma4(acc[rr], bfhi(a1.y), wlv[3]);
                        fma4(acc[rr], bflo(a2.x), wrv[0]);
                        fma4(acc[rr], bfhi(a2.x), wrv[1]);
                        fma4(acc[rr], bflo(a2.y), wrv[2]);
                        fma4(acc[rr], bfhi(a2.y), wrv[3]);
                    }
                }
            }
        }
    }

#pragma unroll
    for (int rr = 0; rr < R; rr++) {
        int n = n0 + rr;
        if (n < nN) {
            float4 v = acc[rr];
            v.x = fmaxf(v.x, 0.f); v.y = fmaxf(v.y, 0.f);
            v.z = fmaxf(v.z, 0.f); v.w = fmaxf(v.w, 0.f);
            if (out) *(float4*)(out + (size_t)n * M + cq) = v;
            if (outb) {
                ushort4 o;
                o.x = f2bf(v.x); o.y = f2bf(v.y);
                o.z = f2bf(v.z); o.w = f2bf(v.w);
                *(ushort4*)(outb + (size_t)n * M + cq) = o;
            }
        }
    }
}

// ---------------- classifier: [N,32] @ [32,2] + bc ----------------

__global__ void classifier_kernel(const float* __restrict__ h,
                                  const float* __restrict__ wc,
                                  const float* __restrict__ bc,
                                  float* __restrict__ out, int nN) {
    int n = blockIdx.x * blockDim.x + threadIdx.x;
    if (n >= nN) return;
    float a0 = bc[0], a1 = bc[1];
    const float* row = h + (size_t)n * 32;
#pragma unroll
    for (int k = 0; k < 32; k++) {
        float v = row[k];
        a0 = fmaf(v, wc[k * 2 + 0], a0);
        a1 = fmaf(v, wc[k * 2 + 1], a1);
    }
    out[n * 2 + 0] = a0;
    out[n * 2 + 1] = a1;
}

// ---------------- launch ----------------

extern "C" void kernel_launch(void* const* d_in, const int* in_sizes, int n_in,
                              void* d_out, int out_size, void* d_ws, size_t ws_size,
                              hipStream_t stream) {
    const float* x   = (const float*)d_in[0];
    const int*   ei  = (const int*)d_in[1];   // [2,E] int32
    const float* w1l = (const float*)d_in[2];
    const float* b1l = (const float*)d_in[3];
    const float* w1r = (const float*)d_in[4];
    const float* w2l = (const float*)d_in[5];
    const float* b2l = (const float*)d_in[6];
    const float* w2r = (const float*)d_in[7];
    const float* w3l = (const float*)d_in[8];
    const float* b3l = (const float*)d_in[9];
    const float* w3r = (const float*)d_in[10];
    const float* wc  = (const float*)d_in[11];
    const float* bc  = (const float*)d_in[12];
    float* out = (float*)d_out;

    const int N = in_sizes[0] / 128;
    const int E = in_sizes[1] / 2;
    const int NB = (N + 511) / 512;           // scan blocks (<=1024)

    char* p = (char*)d_ws;
    auto alloc = [&](size_t bytes) {
        char* r = p;
        p += (bytes + 511) & ~(size_t)511;
        return r;
    };
    int*   deg    = (int*)  alloc((size_t)N * 4);
    int*   offs   = (int*)  alloc(((size_t)N + 1) * 4);
    int*   cursor = (int*)  alloc((size_t)N * 4);
    float* invd   = (float*)alloc((size_t)N * 4);
    int*   bsum   = (int*)  alloc((size_t)NB * 4);
    int*   csr    = (int*)  alloc((size_t)E * 4);
    float* h3     = (float*)alloc((size_t)N * 32 * 4);
    unsigned short* xb    = (unsigned short*)alloc((size_t)N * 128 * 2);
    unsigned short* h1b   = (unsigned short*)alloc((size_t)N * 128 * 2);
    unsigned short* h2b   = (unsigned short*)alloc((size_t)N * 64 * 2);
    unsigned short* meanb = (unsigned short*)alloc((size_t)N * 128 * 2);

    hipMemsetAsync(deg, 0, (size_t)N * 4, stream);
    hipMemsetAsync(cursor, 0, (size_t)N * 4, stream);

    int eb = (E + 255) / 256;
    degree_kernel<<<eb, 256, 0, stream>>>(ei, deg, E);
    block_sum_kernel<<<NB, 512, 0, stream>>>(deg, bsum, N);
    bsum_scan_kernel<<<1, 1024, 0, stream>>>(bsum, NB);
    scan_write_kernel<<<NB, 512, 0, stream>>>(deg, bsum, offs, invd, N, E);
    fill_kernel<<<eb, 256, 0, stream>>>(ei, offs, cursor, csr, E);

    int n4 = N * 128 / 4;
    f32_to_bf16_kernel<<<(n4 + 255) / 256, 256, 0, stream>>>(x, xb, n4);

    int ab = (N + 3) / 4;

    // layer 1-2: R=8 -> rows/block = (512/(M/4))*8; layer 3: R=4
    int g1 = (N + 16384 / 128 - 1) / (16384 / 128);   // 128 rows/blk -> 782
    int g2 = (N + 16384 / 64  - 1) / (16384 / 64);    // 256 rows/blk -> 391
    int g3 = (N + 8192 / 32   - 1) / (8192 / 32);     // 256 rows/blk -> 391

    aggregate_bf16_kernel<128><<<ab, 256, 0, stream>>>(xb, offs, csr, invd, meanb, N);
    gemm_relu_ldsw<128, 128, 8, 4><<<g1, 512, 0, stream>>>(meanb, xb, w1l, w1r, b1l, nullptr, h1b, N);

    aggregate_bf16_kernel<128><<<ab, 256, 0, stream>>>(h1b, offs, csr, invd, meanb, N);
    gemm_relu_ldsw<128, 64, 8, 4><<<g2, 512, 0, stream>>>(meanb, h1b, w2l, w2r, b2l, nullptr, h2b, N);

    aggregate_bf16_kernel<64><<<ab, 256, 0, stream>>>(h2b, offs, csr, invd, meanb, N);
    gemm_relu_ldsw<64, 32, 4, 2><<<g3, 512, 0, stream>>>(meanb, h2b, w3l, w3r, b3l, h3, nullptr, N);

    classifier_kernel<<<(N + 255) / 256, 256, 0, stream>>>(h3, wc, bc, out, N);
}

// Round 22
// 457.012 us; speedup vs baseline: 1.4999x; 1.4999x over previous
//
#include <hip/hip_runtime.h>

// ---------------- CSR build ----------------

__global__ void degree_kernel(const int* __restrict__ ei, int* __restrict__ deg, int E) {
    int e = blockIdx.x * blockDim.x + threadIdx.x;
    if (e < E) {
        int dst = ei[E + e];
        atomicAdd(&deg[dst], 1);
    }
}

__global__ __launch_bounds__(512) void block_sum_kernel(
    const int* __restrict__ deg, int* __restrict__ bsum, int n)
{
    __shared__ int s[512];
    int i = blockIdx.x * 512 + threadIdx.x;
    s[threadIdx.x] = (i < n) ? deg[i] : 0;
    __syncthreads();
#pragma unroll
    for (int off = 256; off > 0; off >>= 1) {
        if (threadIdx.x < off) s[threadIdx.x] += s[threadIdx.x + off];
        __syncthreads();
    }
    if (threadIdx.x == 0) bsum[blockIdx.x] = s[0];
}

__global__ __launch_bounds__(1024) void bsum_scan_kernel(int* __restrict__ bsum, int nb) {
    __shared__ int s[1024];
    int t = threadIdx.x;
    s[t] = (t < nb) ? bsum[t] : 0;
    __syncthreads();
    for (int off = 1; off < 1024; off <<= 1) {
        int v = 0;
        if (t >= off) v = s[t - off];
        __syncthreads();
        if (t >= off) s[t] += v;
        __syncthreads();
    }
    if (t < nb) bsum[t] = (t == 0) ? 0 : s[t - 1];
}

__global__ __launch_bounds__(512) void scan_write_kernel(
    const int* __restrict__ deg, const int* __restrict__ bsum,
    int* __restrict__ offs, float* __restrict__ invd, int n, int E)
{
    __shared__ int s[512];
    int t = threadIdx.x;
    int i = blockIdx.x * 512 + t;
    int d = (i < n) ? deg[i] : 0;
    s[t] = d;
    __syncthreads();
    for (int off = 1; off < 512; off <<= 1) {
        int v = 0;
        if (t >= off) v = s[t - off];
        __syncthreads();
        if (t >= off) s[t] += v;
        __syncthreads();
    }
    if (i < n) {
        offs[i] = bsum[blockIdx.x] + s[t] - d;   // exclusive prefix
        invd[i] = 1.0f / (float)(d > 0 ? d : 1);
    }
    if (blockIdx.x == 0 && t == 0) offs[n] = E;
}

__global__ void fill_kernel(const int* __restrict__ ei, const int* __restrict__ offs,
                            int* __restrict__ cursor, int* __restrict__ csr, int E) {
    int e = blockIdx.x * blockDim.x + threadIdx.x;
    if (e < E) {
        int src = ei[e];
        int dst = ei[E + e];
        int pos = atomicAdd(&cursor[dst], 1);
        csr[offs[dst] + pos] = src;
    }
}

// ---------------- bf16 helpers ----------------

__device__ inline unsigned short f2bf(float f) {
    unsigned int u = __float_as_uint(f);
    return (unsigned short)((u + 0x7fffu + ((u >> 16) & 1u)) >> 16);
}

__device__ inline float bflo(unsigned int u) { return __uint_as_float(u << 16); }
__device__ inline float bfhi(unsigned int u) { return __uint_as_float(u & 0xffff0000u); }

__global__ void f32_to_bf16_kernel(const float* __restrict__ in,
                                   unsigned short* __restrict__ out, int n4) {
    int i = blockIdx.x * blockDim.x + threadIdx.x;
    if (i < n4) {
        float4 v = *(const float4*)(in + (size_t)i * 4);
        ushort4 o;
        o.x = f2bf(v.x); o.y = f2bf(v.y); o.z = f2bf(v.z); o.w = f2bf(v.w);
        *(ushort4*)(out + (size_t)i * 4) = o;
    }
}

// ---------------- mean aggregation over bf16 rows (fp32 accumulate) ----------

__device__ inline void addbf8(float* a, uint4 v) {
    a[0] += bflo(v.x); a[1] += bfhi(v.x);
    a[2] += bflo(v.y); a[3] += bfhi(v.y);
    a[4] += bflo(v.z); a[5] += bfhi(v.z);
    a[6] += bflo(v.w); a[7] += bfhi(v.w);
}

template <int D>
__global__ __launch_bounds__(256) void aggregate_bf16_kernel(
    const unsigned short* __restrict__ hb, const int* __restrict__ offs,
    const int* __restrict__ csr, const float* __restrict__ invd,
    unsigned short* __restrict__ meanb, int nN)
{
    constexpr int LPR = D / 8;      // lanes per row (16 for D=128, 8 for D=64)
    constexpr int G = 64 / LPR;     // neighbor groups per wave (4 or 8)
    int wid = blockIdx.x * 4 + (threadIdx.x >> 6);
    int lane = threadIdx.x & 63;
    if (wid >= nN) return;
    int o0 = offs[wid], o1 = offs[wid + 1];
    const int p = lane / LPR;
    const int col = (lane % LPR) * 8;

    float a0[8] = {0.f, 0.f, 0.f, 0.f, 0.f, 0.f, 0.f, 0.f};
    float a1[8] = {0.f, 0.f, 0.f, 0.f, 0.f, 0.f, 0.f, 0.f};
    int j = o0;
    for (; j + 2 * G <= o1; j += 2 * G) {
        int s0 = csr[j + p];
        int s1 = csr[j + G + p];
        uint4 v0 = *(const uint4*)(hb + (size_t)s0 * D + col);
        uint4 v1 = *(const uint4*)(hb + (size_t)s1 * D + col);
        addbf8(a0, v0);
        addbf8(a1, v1);
    }
    if (j + G <= o1) {
        int s0 = csr[j + p];
        uint4 v0 = *(const uint4*)(hb + (size_t)s0 * D + col);
        addbf8(a0, v0);
        j += G;
    }
    if (j < o1 && p < o1 - j) {      // partial group
        int s1 = csr[j + p];
        uint4 v1 = *(const uint4*)(hb + (size_t)s1 * D + col);
        addbf8(a1, v1);
    }
#pragma unroll
    for (int q = 0; q < 8; q++) a0[q] += a1[q];

#pragma unroll
    for (int m = LPR; m < 64; m <<= 1) {
#pragma unroll
        for (int q = 0; q < 8; q++) a0[q] += __shfl_xor(a0[q], m);
    }

    if (lane < LPR) {
        float iv = invd[wid];
        uint4 o;
        o.x = (unsigned)f2bf(a0[0] * iv) | ((unsigned)f2bf(a0[1] * iv) << 16);
        o.y = (unsigned)f2bf(a0[2] * iv) | ((unsigned)f2bf(a0[3] * iv) << 16);
        o.z = (unsigned)f2bf(a0[4] * iv) | ((unsigned)f2bf(a0[5] * iv) << 16);
        o.w = (unsigned)f2bf(a0[6] * iv) | ((unsigned)f2bf(a0[7] * iv) << 16);
        *(uint4*)(meanb + (size_t)wid * D + col) = o;
    }
}

// ---------------- MFMA dual GEMM ----------------
// D = A·B via mfma_f32_16x16x32_bf16. Fragment layouts:
//   A: lane l holds row (l&15), k = kb*32 + (j/4)*16 + (l>>4)*4 + (j%4)
//   B: lane l holds col (l&15), same k pattern (pre-swizzled by swizzle_w)
//   C/D: col = lane&15, row = (lane>>4)*4 + reg   [verified m89]
// No LDS, no barriers. W fragments stream from L1 (<=64 KB/matrix).

typedef short short8 __attribute__((ext_vector_type(8)));
typedef short short4v __attribute__((ext_vector_type(4)));
typedef float f32x4 __attribute__((ext_vector_type(4)));

__global__ void swizzle_w_kernel(const float* __restrict__ W,
                                 unsigned short* __restrict__ Ws,
                                 int K, int M) {
    int t = blockIdx.x * blockDim.x + threadIdx.x;
    int KB = K >> 5;
    int total = (M >> 4) * KB * 64;
    if (t >= total) return;
    int l = t & 63;
    int kbc = t >> 6;
    int kb = kbc % KB;
    int c = kbc / KB;
    int km = kb * 32 + ((l >> 4) << 2);
    int m = (c << 4) + (l & 15);
    unsigned short o[8];
#pragma unroll
    for (int j = 0; j < 8; j++) {
        int k = km + (j >> 2) * 16 + (j & 3);
        o[j] = f2bf(W[(size_t)k * M + m]);
    }
    *(uint4*)(Ws + (size_t)t * 8) = *(uint4*)o;
}

template <int K, int M>
__global__ __launch_bounds__(512) void gemm_mfma(
    const unsigned short* __restrict__ A1, const unsigned short* __restrict__ A2,
    const unsigned short* __restrict__ w1s, const unsigned short* __restrict__ w2s,
    const float* __restrict__ bias, float* __restrict__ out,
    unsigned short* __restrict__ outb, int nN)
{
    constexpr int KB = K / 32;
    constexpr int CB = M / 16;
    const int l = threadIdx.x & 63;
    const int wv = threadIdx.x >> 6;
    const int rowbase = blockIdx.x * 128 + wv * 16;
    if (rowbase >= nN) return;       // N % 16 == 0 -> waves are all-or-nothing
    const int arow = rowbase + (l & 15);
    const int ksub = (l >> 4) << 2;

    f32x4 acc[CB];
#pragma unroll
    for (int c = 0; c < CB; c++) acc[c] = (f32x4){0.f, 0.f, 0.f, 0.f};

    const unsigned short* a1p = A1 + (size_t)arow * K + ksub;
    const unsigned short* a2p = A2 + (size_t)arow * K + ksub;

#pragma unroll
    for (int kb = 0; kb < KB; kb++) {
        short4v l1 = *(const short4v*)(a1p + kb * 32);
        short4v h1 = *(const short4v*)(a1p + kb * 32 + 16);
        short4v l2 = *(const short4v*)(a2p + kb * 32);
        short4v h2 = *(const short4v*)(a2p + kb * 32 + 16);
        short8 a1 = {l1[0], l1[1], l1[2], l1[3], h1[0], h1[1], h1[2], h1[3]};
        short8 a2 = {l2[0], l2[1], l2[2], l2[3], h2[0], h2[1], h2[2], h2[3]};
#pragma unroll
        for (int c = 0; c < CB; c++) {
            short8 b1 = *(const short8*)(w1s + ((size_t)(c * KB + kb) * 64 + l) * 8);
            acc[c] = __builtin_amdgcn_mfma_f32_16x16x32_bf16(a1, b1, acc[c], 0, 0, 0);
            short8 b2 = *(const short8*)(w2s + ((size_t)(c * KB + kb) * 64 + l) * 8);
            acc[c] = __builtin_amdgcn_mfma_f32_16x16x32_bf16(a2, b2, acc[c], 0, 0, 0);
        }
    }

    const int orow = rowbase + ((l >> 4) << 2);
#pragma unroll
    for (int c = 0; c < CB; c++) {
        int col = (c << 4) + (l & 15);
        float bv = bias[col];
#pragma unroll
        for (int r = 0; r < 4; r++) {
            float v = fmaxf(acc[c][r] + bv, 0.f);
            size_t idx = (size_t)(orow + r) * M + col;
            if (out) out[idx] = v;
            if (outb) outb[idx] = f2bf(v);
        }
    }
}

// ---------------- classifier: [N,32] @ [32,2] + bc ----------------

__global__ void classifier_kernel(const float* __restrict__ h,
                                  const float* __restrict__ wc,
                                  const float* __restrict__ bc,
                                  float* __restrict__ out, int nN) {
    int n = blockIdx.x * blockDim.x + threadIdx.x;
    if (n >= nN) return;
    float a0 = bc[0], a1 = bc[1];
    const float* row = h + (size_t)n * 32;
#pragma unroll
    for (int k = 0; k < 32; k++) {
        float v = row[k];
        a0 = fmaf(v, wc[k * 2 + 0], a0);
        a1 = fmaf(v, wc[k * 2 + 1], a1);
    }
    out[n * 2 + 0] = a0;
    out[n * 2 + 1] = a1;
}

// ---------------- launch ----------------

extern "C" void kernel_launch(void* const* d_in, const int* in_sizes, int n_in,
                              void* d_out, int out_size, void* d_ws, size_t ws_size,
                              hipStream_t stream) {
    const float* x   = (const float*)d_in[0];
    const int*   ei  = (const int*)d_in[1];   // [2,E] int32
    const float* w1l = (const float*)d_in[2];
    const float* b1l = (const float*)d_in[3];
    const float* w1r = (const float*)d_in[4];
    const float* w2l = (const float*)d_in[5];
    const float* b2l = (const float*)d_in[6];
    const float* w2r = (const float*)d_in[7];
    const float* w3l = (const float*)d_in[8];
    const float* b3l = (const float*)d_in[9];
    const float* w3r = (const float*)d_in[10];
    const float* wc  = (const float*)d_in[11];
    const float* bc  = (const float*)d_in[12];
    float* out = (float*)d_out;

    const int N = in_sizes[0] / 128;
    const int E = in_sizes[1] / 2;
    const int NB = (N + 511) / 512;           // scan blocks (<=1024)

    char* p = (char*)d_ws;
    auto alloc = [&](size_t bytes) {
        char* r = p;
        p += (bytes + 511) & ~(size_t)511;
        return r;
    };
    int*   deg    = (int*)  alloc((size_t)N * 4);
    int*   offs   = (int*)  alloc(((size_t)N + 1) * 4);
    int*   cursor = (int*)  alloc((size_t)N * 4);
    float* invd   = (float*)alloc((size_t)N * 4);
    int*   bsum   = (int*)  alloc((size_t)NB * 4);
    int*   csr    = (int*)  alloc((size_t)E * 4);
    float* h3     = (float*)alloc((size_t)N * 32 * 4);
    unsigned short* xb    = (unsigned short*)alloc((size_t)N * 128 * 2);
    unsigned short* h1b   = (unsigned short*)alloc((size_t)N * 128 * 2);
    unsigned short* h2b   = (unsigned short*)alloc((size_t)N * 64 * 2);
    unsigned short* meanb = (unsigned short*)alloc((size_t)N * 128 * 2);
    unsigned short* w1ls  = (unsigned short*)alloc(128 * 128 * 2);
    unsigned short* w1rs  = (unsigned short*)alloc(128 * 128 * 2);
    unsigned short* w2ls  = (unsigned short*)alloc(128 * 64 * 2);
    unsigned short* w2rs  = (unsigned short*)alloc(128 * 64 * 2);
    unsigned short* w3ls  = (unsigned short*)alloc(64 * 32 * 2);
    unsigned short* w3rs  = (unsigned short*)alloc(64 * 32 * 2);

    hipMemsetAsync(deg, 0, (size_t)N * 4, stream);
    hipMemsetAsync(cursor, 0, (size_t)N * 4, stream);

    int eb = (E + 255) / 256;
    degree_kernel<<<eb, 256, 0, stream>>>(ei, deg, E);
    block_sum_kernel<<<NB, 512, 0, stream>>>(deg, bsum, N);
    bsum_scan_kernel<<<1, 1024, 0, stream>>>(bsum, NB);
    scan_write_kernel<<<NB, 512, 0, stream>>>(deg, bsum, offs, invd, N, E);
    fill_kernel<<<eb, 256, 0, stream>>>(ei, offs, cursor, csr, E);

    int n4 = N * 128 / 4;
    f32_to_bf16_kernel<<<(n4 + 255) / 256, 256, 0, stream>>>(x, xb, n4);

    // weight swizzle (tiny)
    swizzle_w_kernel<<<(128 * 128 / 8 + 255) / 256, 256, 0, stream>>>(w1l, w1ls, 128, 128);
    swizzle_w_kernel<<<(128 * 128 / 8 + 255) / 256, 256, 0, stream>>>(w1r, w1rs, 128, 128);
    swizzle_w_kernel<<<(128 * 64 / 8 + 255) / 256, 256, 0, stream>>>(w2l, w2ls, 128, 64);
    swizzle_w_kernel<<<(128 * 64 / 8 + 255) / 256, 256, 0, stream>>>(w2r, w2rs, 128, 64);
    swizzle_w_kernel<<<(64 * 32 / 8 + 255) / 256, 256, 0, stream>>>(w3l, w3ls, 64, 32);
    swizzle_w_kernel<<<(64 * 32 / 8 + 255) / 256, 256, 0, stream>>>(w3r, w3rs, 64, 32);

    int ab = (N + 3) / 4;
    int gm = (N + 127) / 128;     // 128 rows per MFMA block

    aggregate_bf16_kernel<128><<<ab, 256, 0, stream>>>(xb, offs, csr, invd, meanb, N);
    gemm_mfma<128, 128><<<gm, 512, 0, stream>>>(meanb, xb, w1ls, w1rs, b1l, nullptr, h1b, N);

    aggregate_bf16_kernel<128><<<ab, 256, 0, stream>>>(h1b, offs, csr, invd, meanb, N);
    gemm_mfma<128, 64><<<gm, 512, 0, stream>>>(meanb, h1b, w2ls, w2rs, b2l, nullptr, h2b, N);

    aggregate_bf16_kernel<64><<<ab, 256, 0, stream>>>(h2b, offs, csr, invd, meanb, N);
    gemm_mfma<64, 32><<<gm, 512, 0, stream>>>(meanb, h2b, w3ls, w3rs, b3l, h3, nullptr, N);

    classifier_kernel<<<(N + 255) / 256, 256, 0, stream>>>(h3, wc, bc, out, N);
}